// Round 13
// baseline (244.528 us; speedup 1.0000x reference)
//
#include <hip/hip_runtime.h>
#include <hip/hip_bf16.h>
#include <stdint.h>

// MultiHeadedAttention: B=2, D_MODEL=1024, N=2048, H=16, HD=64.
// fp32 I/O, bf16 internal. Round 13: attn split-K2 (additive max-free fp32
// partials, 2048 blocks -> LDS-capped 5 blocks/CU vs 4) + comb_k. R6's split
// was neutral because the kernel was LDS-conflict-bound then (29M cycles);
// conflicts are now 8.4M and attn is wave-starved (Occ 32% @ 81% issue).
#define DM 1024
#define NS 2048
#define NH 16
#define HD 64

typedef unsigned short u16;
typedef __attribute__((ext_vector_type(8))) short short8;
typedef __attribute__((ext_vector_type(4))) short s16x4;
typedef __attribute__((ext_vector_type(8))) unsigned short u16x8;
typedef __attribute__((ext_vector_type(4))) float f32x4;
typedef __attribute__((ext_vector_type(4))) unsigned short u16x4;

// gfx90a+ legacy-shape MFMA, present on gfx950 (ISA §10: v_mfma_f32_16x16x16_bf16)
#define MFMA_PV(a, b, c) __builtin_amdgcn_mfma_f32_16x16x16bf16_1k(a, b, c, 0, 0, 0)

// packed RNE fp32x2 -> bf16x2 (v_cvt_pk_bf16_f32 where HW supports it)
static __device__ __forceinline__ uint32_t pkbf(float a, float b) {
  union { __hip_bfloat162 h; uint32_t u; } cv;
  cv.h = __float22bfloat162_rn(float2{a, b});
  return cv.u;
}
static __device__ __forceinline__ u16x4 pkbf4(float a, float b, float c, float d) {
  union { uint32_t u[2]; u16x4 v; } cv;
  cv.u[0] = pkbf(a, b); cv.u[1] = pkbf(c, d);
  return cv.v;
}
static __device__ __forceinline__ s16x4 pkbf4s(float a, float b, float c, float d) {
  union { uint32_t u[2]; s16x4 v; } cv;
  cv.u[0] = pkbf(a, b); cv.u[1] = pkbf(c, d);
  return cv.v;
}
// async global->LDS, 16B/lane; LDS side wave-uniform base + lane*16 at all sites.
static __device__ __forceinline__ void gload16(u16* lds, const u16* g) {
  auto l = (__attribute__((address_space(3))) uint32_t*)(uint32_t)(uintptr_t)lds;
  auto gp = (const __attribute__((address_space(1))) uint32_t*)(uintptr_t)g;
  __builtin_amdgcn_global_load_lds(gp, l, 16, 0, 0);
}

// -------- weight convert: 3x fp32[DM*DM] -> bf16 (Wq, Wk, Wv) --------
__global__ __launch_bounds__(256) void cvt3_k(const float* __restrict__ a,
                                              const float* __restrict__ b,
                                              const float* __restrict__ c,
                                              u16* __restrict__ oa, u16* __restrict__ ob,
                                              u16* __restrict__ oc) {
  const int y = blockIdx.y;
  const float* in = y == 0 ? a : y == 1 ? b : c;
  u16* out = y == 0 ? oa : y == 1 ? ob : oc;
  int i = (blockIdx.x * 256 + threadIdx.x) * 4;
  f32x4 v = *(const f32x4*)(in + i);
  *(u16x4*)(out + i) = pkbf4(v.x, v.y, v.z, v.w);
}

// -------- Wm convert + column permute: out[c][h*64+d] = bf16(in[c][d*16+h]) --
__global__ __launch_bounds__(256) void cvtp_k(const float* __restrict__ in,
                                              u16* __restrict__ out) {
  __shared__ __attribute__((aligned(16))) u16 t[4][16][68];  // [row][h][d]
  const int tid = threadIdx.x;
  const int rr = tid >> 6, tl = tid & 63;
  const int row = blockIdx.x * 4 + rr;
  const float* ip = in + (size_t)row * DM;
  u16* op = out + (size_t)row * DM;
#pragma unroll
  for (int e = 0; e < 4; ++e) {
    int i = e * 256 + tl * 4;
    f32x4 v = *(const f32x4*)(ip + i);
    u16x4 bb = pkbf4(v.x, v.y, v.z, v.w);
    int d = i >> 4, h0 = i & 15;
    t[rr][h0 + 0][d] = bb.x; t[rr][h0 + 1][d] = bb.y;
    t[rr][h0 + 2][d] = bb.z; t[rr][h0 + 3][d] = bb.w;
  }
  __syncthreads();
#pragma unroll
  for (int e = 0; e < 4; ++e) {
    int j = e * 256 + tl * 4;
    int h = j >> 6, d = j & 63;
    u16x4 v;
    v.x = t[rr][h][d + 0]; v.y = t[rr][h][d + 1];
    v.z = t[rr][h][d + 2]; v.w = t[rr][h][d + 3];
    *(u16x4*)(op + j) = v;
  }
}

// -------- fused input transpose+downcast: fp32 [DM][NS] -> bf16 [NS][DM] -----
__global__ __launch_bounds__(256) void trf3_k(const float* __restrict__ q,
                                              const float* __restrict__ k,
                                              const float* __restrict__ v,
                                              u16* __restrict__ oq, u16* __restrict__ ok,
                                              u16* __restrict__ ov) {
  __shared__ __attribute__((aligned(16))) u16 t[64][65];
  const int z = blockIdx.z, b = z & 1, which = z >> 1;
  const float* in = which == 0 ? q : which == 1 ? k : v;
  u16* out = which == 0 ? oq : which == 1 ? ok : ov;
  const float* ip = in + (size_t)b * DM * NS;
  u16* op = out + (size_t)b * DM * NS;
  const int r0 = blockIdx.y * 64, c0 = blockIdx.x * 64;
  const int tx = threadIdx.x, ty = threadIdx.y;  // 16x16
#pragma unroll
  for (int j = 0; j < 4; ++j) {
    int row = ty + j * 16;
    f32x4 vv = *(const f32x4*)(ip + (size_t)(r0 + row) * NS + c0 + tx * 4);
    u16x4 bb = pkbf4(vv.x, vv.y, vv.z, vv.w);
    t[row][tx * 4 + 0] = bb.x; t[row][tx * 4 + 1] = bb.y;
    t[row][tx * 4 + 2] = bb.z; t[row][tx * 4 + 3] = bb.w;
  }
  __syncthreads();
#pragma unroll
  for (int j = 0; j < 4; ++j) {
    int crow = ty + j * 16;
    u16x4 vv;
    vv.x = t[tx * 4 + 0][crow]; vv.y = t[tx * 4 + 1][crow];
    vv.z = t[tx * 4 + 2][crow]; vv.w = t[tx * 4 + 3][crow];
    *(u16x4*)(op + (size_t)(c0 + crow) * DM + r0 + tx * 4) = vv;
  }
}

// ---------------- fused QKV projection GEMM ----------------
__global__ __launch_bounds__(256) void qkv_k(
    const u16* __restrict__ Xq, const u16* __restrict__ Xk, const u16* __restrict__ Xv,
    const u16* __restrict__ Wq, const u16* __restrict__ Wk, const u16* __restrict__ Wv,
    const float* __restrict__ bq, const float* __restrict__ bk, const float* __restrict__ bv,
    u16* __restrict__ QH, u16* __restrict__ KH, u16* __restrict__ VH) {
  __shared__ __attribute__((aligned(16))) u16 As[128 * 32];
  __shared__ __attribute__((aligned(16))) u16 Bs[128 * 32];
  const int z = blockIdx.z, b = z & 1, which = z >> 1;
  const u16* X = which == 0 ? Xq : which == 1 ? Xk : Xv;
  const u16* W = which == 0 ? Wq : which == 1 ? Wk : Wv;
  const float* bias = which == 0 ? bq : which == 1 ? bk : bv;
  u16* out = which == 0 ? QH : which == 1 ? KH : VH;
  const float sc = which == 0 ? 0.18033688011112042f : 1.0f;  // 0.125*log2e
  const int m0 = blockIdx.x * 128;
  const int c0 = blockIdx.y * 128;
  const u16* Xb = X + (size_t)b * NS * DM;
  const int tid = threadIdx.x;
  const int lane = tid & 63, w = tid >> 6;
  const int wm = w >> 1, wc = w & 1;
  const int qd = lane >> 4, ml = lane & 15;
  const int sml = (ml >> 1) & 3;  // read-side swizzle key

  f32x4 acc[4][4];
#pragma unroll
  for (int i = 0; i < 4; ++i)
#pragma unroll
    for (int j = 0; j < 4; ++j) acc[i][j] = (f32x4){0.f, 0.f, 0.f, 0.f};

  for (int k0 = 0; k0 < DM; k0 += 32) {
    __syncthreads();
#pragma unroll
    for (int it = 0; it < 2; ++it) {
      int ci = it * 256 + tid;
      int row = ci >> 2;
      int jg = (ci & 3) ^ ((ci >> 3) & 3);  // chunk swizzle (row>>1)&3
      gload16(&As[ci * 8], Xb + (size_t)(m0 + row) * DM + k0 + jg * 8);
      gload16(&Bs[ci * 8], W + (size_t)(c0 + row) * DM + k0 + jg * 8);
    }
    __syncthreads();
    short8 af[4], bf[4];
#pragma unroll
    for (int i = 0; i < 4; ++i) {
      af[i] = *(const short8*)&As[(wm * 64 + i * 16 + ml) * 32 + ((qd ^ sml) * 8)];
      bf[i] = *(const short8*)&Bs[(wc * 64 + i * 16 + ml) * 32 + ((qd ^ sml) * 8)];
    }
#pragma unroll
    for (int mi = 0; mi < 4; ++mi)
#pragma unroll
      for (int ci2 = 0; ci2 < 4; ++ci2)
        acc[mi][ci2] = __builtin_amdgcn_mfma_f32_16x16x32_bf16(af[mi], bf[ci2],
                                                               acc[mi][ci2], 0, 0, 0);
  }

  const int cw = c0 + wc * 64;
  const int mw = m0 + wm * 64;
  float bv4[4];
#pragma unroll
  for (int ci2 = 0; ci2 < 4; ++ci2) bv4[ci2] = bias[cw + ci2 * 16 + ml];

  if (which < 2) {
    const int h = ml, d0 = cw >> 4;
    u16* ob = out + ((size_t)(b * NH + h) * NS) * HD;
#pragma unroll
    for (int mi = 0; mi < 4; ++mi) {
#pragma unroll
      for (int r = 0; r < 4; ++r) {
        int n = mw + mi * 16 + qd * 4 + r;
        *(u16x4*)(ob + (size_t)n * HD + d0) =
            pkbf4((acc[mi][0][r] + bv4[0]) * sc, (acc[mi][1][r] + bv4[1]) * sc,
                  (acc[mi][2][r] + bv4[2]) * sc, (acc[mi][3][r] + bv4[3]) * sc);
      }
    }
  } else {
#pragma unroll
    for (int ci2 = 0; ci2 < 4; ++ci2) {
      int c = cw + ci2 * 16 + ml;
      int h = c & 15, d = c >> 4;
#pragma unroll
      for (int mi = 0; mi < 4; ++mi) {
        int nb = mw + mi * 16 + qd * 4;
        *(u16x4*)(out + ((size_t)(b * NH + h) * HD + d) * NS + nb) =
            pkbf4(acc[mi][ci2][0] + bv4[ci2], acc[mi][ci2][1] + bv4[ci2],
                  acc[mi][ci2][2] + bv4[ci2], acc[mi][ci2][3] + bv4[ci2]);
      }
    }
  }
}

// ---------------- output projection, 64x128 tiles (fp32 out) ----------------
// X: [b][n][j] (j = h*64+d, attn output), W: Wm' with permuted columns.
__global__ __launch_bounds__(256) void proj_o(const u16* __restrict__ X,
                                              const u16* __restrict__ W,
                                              const float* __restrict__ bias,
                                              float* __restrict__ out) {
  __shared__ __attribute__((aligned(16))) u16 As[64 * 32];
  __shared__ __attribute__((aligned(16))) u16 Bs[128 * 32];
  const int b = blockIdx.z;
  const int m0 = blockIdx.x * 64;
  const int c0 = blockIdx.y * 128;
  const u16* Xb = X + (size_t)b * NS * DM;
  const int tid = threadIdx.x;
  const int lane = tid & 63, w = tid >> 6;
  const int wm = w >> 1, wc = w & 1;  // wave tile: 32 rows x 64 cols
  const int qd = lane >> 4, ml = lane & 15;
  const int sml = (ml >> 1) & 3;

  f32x4 acc[2][4];
#pragma unroll
  for (int i = 0; i < 2; ++i)
#pragma unroll
    for (int j = 0; j < 4; ++j) acc[i][j] = (f32x4){0.f, 0.f, 0.f, 0.f};

  for (int k0 = 0; k0 < DM; k0 += 32) {
    __syncthreads();
    {  // A: 256 chunks (64 rows x 4), one per thread
      int jg = (tid & 3) ^ ((tid >> 3) & 3);
      int row = tid >> 2;
      gload16(&As[tid * 8], Xb + (size_t)(m0 + row) * DM + k0 + jg * 8);
    }
#pragma unroll
    for (int it = 0; it < 2; ++it) {  // B: 512 chunks (128 rows x 4)
      int ci = it * 256 + tid;
      int row = ci >> 2;
      int jg = (ci & 3) ^ ((ci >> 3) & 3);
      gload16(&Bs[ci * 8], W + (size_t)(c0 + row) * DM + k0 + jg * 8);
    }
    __syncthreads();
    short8 af[2], bf[4];
#pragma unroll
    for (int i = 0; i < 2; ++i)
      af[i] = *(const short8*)&As[(wm * 32 + i * 16 + ml) * 32 + ((qd ^ sml) * 8)];
#pragma unroll
    for (int i = 0; i < 4; ++i)
      bf[i] = *(const short8*)&Bs[(wc * 64 + i * 16 + ml) * 32 + ((qd ^ sml) * 8)];
#pragma unroll
    for (int mi = 0; mi < 2; ++mi)
#pragma unroll
      for (int ci2 = 0; ci2 < 4; ++ci2)
        acc[mi][ci2] = __builtin_amdgcn_mfma_f32_16x16x32_bf16(af[mi], bf[ci2],
                                                               acc[mi][ci2], 0, 0, 0);
  }

  const int cw = c0 + wc * 64;
  const int mw = m0 + wm * 32;
#pragma unroll
  for (int ci2 = 0; ci2 < 4; ++ci2) {
    int c = cw + ci2 * 16 + ml;
    float bv = bias[c];
#pragma unroll
    for (int mi = 0; mi < 2; ++mi) {
      int nb = mw + mi * 16 + qd * 4;
      f32x4 v;
      v.x = acc[mi][ci2][0] + bv; v.y = acc[mi][ci2][1] + bv;
      v.z = acc[mi][ci2][2] + bv; v.w = acc[mi][ci2][3] + bv;
      *(f32x4*)(out + ((size_t)b * DM + c) * NS + nb) = v;
    }
  }
}

// ---------------- flash attention, split-K2, register-P, async dbuf ----------
// Q,K: [bh][n][d] (Q pre-scaled), V: [bh][d][n]. grid (NS/64, 32, 2).
// Each block: 64 q-rows x 1024 keys. Writes unnormalized fp32 O^T partial
// ([b][n][j], j=h*64+d) + l partial ([half][bh][n]). ONE barrier per tile.
__global__ __launch_bounds__(256) void attn_k(const u16* __restrict__ Q,
                                              const u16* __restrict__ K,
                                              const u16* __restrict__ V,
                                              float* __restrict__ O0,
                                              float* __restrict__ O1,
                                              float* __restrict__ lp) {
  __shared__ __attribute__((aligned(16))) u16 Ks[2 * 2 * 2048];  // [buf][slab][64][32]
  __shared__ __attribute__((aligned(16))) u16 Vs[2 * 2 * 2048];  // [buf][slab][64 d][32]
  const int bh = blockIdx.y, b = bh >> 4, h = bh & 15;
  const int half = blockIdx.z;
  const int n0 = blockIdx.x * 64;
  const u16* Qb = Q + (size_t)bh * NS * HD;
  const u16* Kb = K + (size_t)bh * NS * HD + (size_t)half * (NS / 2) * HD;
  const u16* Vb = V + (size_t)bh * HD * NS + (size_t)half * (NS / 2);
  const int tid = threadIdx.x, lane = tid & 63, w = tid >> 6;
  const int qd = lane >> 4, ml = lane & 15;
  const int sml = (ml >> 1) & 3;

  // Q fragments straight from global
  short8 aq[2];
  {
    const u16* qr = Qb + (size_t)(n0 + w * 16 + ml) * HD + qd * 8;
    aq[0] = *(const short8*)qr;
    aq[1] = *(const short8*)(qr + 32);
  }

  const int srow = tid >> 2;                       // staging row (key or d)
  const int jg = (tid & 3) ^ ((tid >> 3) & 3);     // swizzled 16B chunk

  // prologue: tile 0 -> buf 0
#pragma unroll
  for (int s = 0; s < 2; ++s) {
    gload16(&Ks[s * 2048 + tid * 8], Kb + (size_t)srow * HD + s * 32 + jg * 8);
    gload16(&Vs[s * 2048 + tid * 8], Vb + (size_t)srow * NS + s * 32 + jg * 8);
  }
  __syncthreads();

  f32x4 O[4];
#pragma unroll
  for (int i = 0; i < 4; ++i) O[i] = (f32x4){0.f, 0.f, 0.f, 0.f};
  f32x4 lsum4 = (f32x4){0.f, 0.f, 0.f, 0.f};

  const int NT = (NS / 2) / 64;  // 16 tiles per half
  for (int kb = 0; kb < NT; ++kb) {
    const int cur = kb & 1, nxt = cur ^ 1;
    if (kb < NT - 1) {  // prefetch tile kb+1 into the other buffer
#pragma unroll
      for (int s = 0; s < 2; ++s) {
        gload16(&Ks[(nxt * 2 + s) * 2048 + tid * 8],
                Kb + (size_t)((kb + 1) * 64 + srow) * HD + s * 32 + jg * 8);
        gload16(&Vs[(nxt * 2 + s) * 2048 + tid * 8],
                Vb + (size_t)srow * NS + (kb + 1) * 64 + s * 32 + jg * 8);
      }
    }

    // S^T = K Q^T  (D[key][qrow]; A=K frag, B=Q frag)
    const u16* kbase = &Ks[cur * 2 * 2048];
    f32x4 S[4];
#pragma unroll
    for (int f = 0; f < 4; ++f) S[f] = (f32x4){0.f, 0.f, 0.f, 0.f};
#pragma unroll
    for (int f = 0; f < 4; ++f)
#pragma unroll
      for (int ks = 0; ks < 2; ++ks) {
        short8 bk = *(const short8*)&kbase[ks * 2048 + (f * 16 + ml) * 32 +
                                           ((qd ^ sml) * 8)];
        S[f] = __builtin_amdgcn_mfma_f32_16x16x32_bf16(bk, aq[ks], S[f], 0, 0, 0);
      }

    // P = exp2(S^T) in registers; packed cvt to MFMA frags
    s16x4 pf[4];
#pragma unroll
    for (int f = 0; f < 4; ++f) {
      f32x4 p;
      p.x = __builtin_amdgcn_exp2f(S[f][0]);
      p.y = __builtin_amdgcn_exp2f(S[f][1]);
      p.z = __builtin_amdgcn_exp2f(S[f][2]);
      p.w = __builtin_amdgcn_exp2f(S[f][3]);
      lsum4 += p;
      pf[f] = pkbf4s(p.x, p.y, p.z, p.w);
    }

    // O^T += V P  (A=V frag, B=P frag; 16 keys per step)
    const u16* vbase = &Vs[cur * 2 * 2048];
#pragma unroll
    for (int t = 0; t < 4; ++t) {
      const int vs = t >> 1;
      const int voff = ((((t & 1) * 2 + (qd >> 1)) ^ sml) * 8) + (qd & 1) * 4;
#pragma unroll
      for (int df = 0; df < 4; ++df) {
        s16x4 vb = *(const s16x4*)&vbase[vs * 2048 + (df * 16 + ml) * 32 + voff];
        O[df] = MFMA_PV(vb, pf[t], O[df]);
      }
    }
    __syncthreads();  // readers of cur done + prefetch into nxt drained
  }

  // partial row sums for qrow=ml over this quad's keys; reduce over quads
  float lsum = (lsum4.x + lsum4.y) + (lsum4.z + lsum4.w);
  lsum += __shfl_xor(lsum, 16);
  lsum += __shfl_xor(lsum, 32);
  if (lane < 16)  // one copy per q-row
    lp[((size_t)(half * 32 + bh)) * NS + n0 + w * 16 + ml] = lsum;

  // O^T partial: lane holds O[d = df*16+qd*4+reg][qrow=ml] -> [b][n][h*64+d]
  float* Op = half ? O1 : O0;
  float* xb = Op + ((size_t)(b * NS) + n0 + w * 16 + ml) * DM + h * 64;
#pragma unroll
  for (int df = 0; df < 4; ++df)
    *(f32x4*)(xb + df * 16 + qd * 4) = O[df];
}

// ---------------- combine: XO[b][n][j] = bf16((O0+O1)/(l0+l1)) ---------------
__global__ __launch_bounds__(256) void comb_k(const float* __restrict__ O0,
                                              const float* __restrict__ O1,
                                              const float* __restrict__ lp,
                                              u16* __restrict__ XO) {
  const size_t t = (size_t)blockIdx.x * 256 + threadIdx.x;  // f32x4 idx over [b][n][j]
  const int j4 = (int)(t & (DM / 4 - 1));    // 8 bits
  const int n = (int)((t >> 8) & (NS - 1));  // 11 bits
  const int b = (int)(t >> 19);
  const int h = j4 >> 4;                     // j = j4*4 -> h = j/64
  f32x4 o0 = *(const f32x4*)(O0 + t * 4);
  f32x4 o1 = *(const f32x4*)(O1 + t * 4);
  const float l0 = lp[((size_t)(b * 16 + h)) * NS + n];
  const float l1 = lp[((size_t)(32 + b * 16 + h)) * NS + n];
  const float linv = 1.f / (l0 + l1);
  *(u16x4*)(XO + t * 4) = pkbf4((o0.x + o1.x) * linv, (o0.y + o1.y) * linv,
                                (o0.z + o1.z) * linv, (o0.w + o1.w) * linv);
}

extern "C" void kernel_launch(void* const* d_in, const int* in_sizes, int n_in,
                              void* d_out, int out_size, void* d_ws, size_t ws_size,
                              hipStream_t stream) {
  const float* query = (const float*)d_in[0];
  const float* key = (const float*)d_in[1];
  const float* value = (const float*)d_in[2];
  const float* Wq = (const float*)d_in[3]; const float* bq = (const float*)d_in[4];
  const float* Wk = (const float*)d_in[5]; const float* bk = (const float*)d_in[6];
  const float* Wv = (const float*)d_in[7]; const float* bv = (const float*)d_in[8];
  const float* Wm = (const float*)d_in[9]; const float* bm = (const float*)d_in[10];

  u16* ws = (u16*)d_ws;
  const size_t TS = (size_t)2 * NS * DM;   // 4,194,304 u16 elems
  const size_t WSZ = (size_t)DM * DM;
  u16* XTq = ws;               // dead after qkv_k
  u16* XTk = ws + TS;          // dead after qkv_k
  u16* XTv = ws + 2 * TS;      // dead after qkv_k
  u16* QH = ws + 3 * TS;
  u16* KH = ws + 4 * TS;
  u16* VH = ws + 5 * TS;
  u16* Wqb = ws + 6 * TS;
  u16* Wkb = Wqb + WSZ;
  u16* Wvb = Wkb + WSZ;
  u16* Wmb = Wvb + WSZ;        // Wm with permuted columns (j = h*64+d)
  // phase-2 overlays: O0 (fp32, 2*NS*DM) covers XTq+XTk exactly; XO covers XTv
  float* O0 = (float*)ws;
  float* O1 = (float*)(ws + 6 * TS + 4 * WSZ);   // fresh region, +16.78 MB
  float* lp = O1 + (size_t)2 * NS * DM;          // +0.5 MB
  u16* XO = XTv;               // attn combined out [b][n][h*64+d]

  cvt3_k<<<dim3(WSZ / 1024, 3), 256, 0, stream>>>(Wq, Wk, Wv, Wqb, Wkb, Wvb);
  cvtp_k<<<DM / 4, 256, 0, stream>>>(Wm, Wmb);

  dim3 tb(16, 16);
  trf3_k<<<dim3(NS / 64, DM / 64, 6), tb, 0, stream>>>(query, key, value, XTq, XTk, XTv);

  qkv_k<<<dim3(NS / 128, DM / 128, 6), 256, 0, stream>>>(
      XTq, XTk, XTv, Wqb, Wkb, Wvb, bq, bk, bv, QH, KH, VH);

  attn_k<<<dim3(NS / 64, 32, 2), 256, 0, stream>>>(QH, KH, VH, O0, O1, lp);
  comb_k<<<(2 * NS * DM / 4) / 256, 256, 0, stream>>>(O0, O1, lp, XO);

  proj_o<<<dim3(NS / 64, DM / 128, 2), 256, 0, stream>>>(XO, Wmb, bm, (float*)d_out);
}

// Round 14
// 236.950 us; speedup vs baseline: 1.0320x; 1.0320x over previous
//
#include <hip/hip_runtime.h>
#include <hip/hip_bf16.h>
#include <stdint.h>

// MultiHeadedAttention: B=2, D_MODEL=1024, N=2048, H=16, HD=64.
// fp32 I/O, bf16 internal. Round 14: split-K reverted (twice-measured neutral).
// attn: 128 q-rows/block (two 16-row fragment sets per wave) -> K/V staging,
// ds_reads, barriers, conflicts all halve chip-wide at unchanged MFMA/exp.
// cvt3+cvtp merged into cvtw_k (one fewer dispatch).
#define DM 1024
#define NS 2048
#define NH 16
#define HD 64

typedef unsigned short u16;
typedef __attribute__((ext_vector_type(8))) short short8;
typedef __attribute__((ext_vector_type(4))) short s16x4;
typedef __attribute__((ext_vector_type(8))) unsigned short u16x8;
typedef __attribute__((ext_vector_type(4))) float f32x4;
typedef __attribute__((ext_vector_type(4))) unsigned short u16x4;

// gfx90a+ legacy-shape MFMA, present on gfx950 (ISA §10: v_mfma_f32_16x16x16_bf16)
#define MFMA_PV(a, b, c) __builtin_amdgcn_mfma_f32_16x16x16bf16_1k(a, b, c, 0, 0, 0)

// packed RNE fp32x2 -> bf16x2 (v_cvt_pk_bf16_f32 where HW supports it)
static __device__ __forceinline__ uint32_t pkbf(float a, float b) {
  union { __hip_bfloat162 h; uint32_t u; } cv;
  cv.h = __float22bfloat162_rn(float2{a, b});
  return cv.u;
}
static __device__ __forceinline__ u16x4 pkbf4(float a, float b, float c, float d) {
  union { uint32_t u[2]; u16x4 v; } cv;
  cv.u[0] = pkbf(a, b); cv.u[1] = pkbf(c, d);
  return cv.v;
}
static __device__ __forceinline__ s16x4 pkbf4s(float a, float b, float c, float d) {
  union { uint32_t u[2]; s16x4 v; } cv;
  cv.u[0] = pkbf(a, b); cv.u[1] = pkbf(c, d);
  return cv.v;
}
// async global->LDS, 16B/lane; LDS side wave-uniform base + lane*16 at all sites.
static __device__ __forceinline__ void gload16(u16* lds, const u16* g) {
  auto l = (__attribute__((address_space(3))) uint32_t*)(uint32_t)(uintptr_t)lds;
  auto gp = (const __attribute__((address_space(1))) uint32_t*)(uintptr_t)g;
  __builtin_amdgcn_global_load_lds(gp, l, 16, 0, 0);
}

// -------- merged weight prep: y<3 plain cvt (Wq,Wk,Wv); y==3 Wm cvt+permute --
// y==3: out[c][h*64+d] = bf16(in[c][d*16+h]); one c-row per block.
__global__ __launch_bounds__(256) void cvtw_k(
    const float* __restrict__ wq, const float* __restrict__ wk,
    const float* __restrict__ wv, const float* __restrict__ wm,
    u16* __restrict__ oq, u16* __restrict__ ok,
    u16* __restrict__ ov, u16* __restrict__ om) {
  __shared__ __attribute__((aligned(16))) u16 t[16][68];
  const int y = blockIdx.y, tid = threadIdx.x;
  if (y < 3) {
    const float* in = y == 0 ? wq : y == 1 ? wk : wv;
    u16* out = y == 0 ? oq : y == 1 ? ok : ov;
    int i = (blockIdx.x * 256 + tid) * 4;
    f32x4 v = *(const f32x4*)(in + i);
    *(u16x4*)(out + i) = pkbf4(v.x, v.y, v.z, v.w);
  } else {
    const int row = blockIdx.x;
    const float* ip = wm + (size_t)row * DM;
    u16* op = om + (size_t)row * DM;
    int i = tid * 4;                       // i = d*16 + h, h0 = i&15
    f32x4 v = *(const f32x4*)(ip + i);
    u16x4 bb = pkbf4(v.x, v.y, v.z, v.w);
    int d = i >> 4, h0 = i & 15;
    t[h0 + 0][d] = bb.x; t[h0 + 1][d] = bb.y;
    t[h0 + 2][d] = bb.z; t[h0 + 3][d] = bb.w;
    __syncthreads();
    int j = tid * 4;                       // j = h*64 + d
    int h = j >> 6, dd = j & 63;
    u16x4 o;
    o.x = t[h][dd + 0]; o.y = t[h][dd + 1];
    o.z = t[h][dd + 2]; o.w = t[h][dd + 3];
    *(u16x4*)(op + j) = o;
  }
}

// -------- fused input transpose+downcast: fp32 [DM][NS] -> bf16 [NS][DM] -----
__global__ __launch_bounds__(256) void trf3_k(const float* __restrict__ q,
                                              const float* __restrict__ k,
                                              const float* __restrict__ v,
                                              u16* __restrict__ oq, u16* __restrict__ ok,
                                              u16* __restrict__ ov) {
  __shared__ __attribute__((aligned(16))) u16 t[64][65];
  const int z = blockIdx.z, b = z & 1, which = z >> 1;
  const float* in = which == 0 ? q : which == 1 ? k : v;
  u16* out = which == 0 ? oq : which == 1 ? ok : ov;
  const float* ip = in + (size_t)b * DM * NS;
  u16* op = out + (size_t)b * DM * NS;
  const int r0 = blockIdx.y * 64, c0 = blockIdx.x * 64;
  const int tx = threadIdx.x, ty = threadIdx.y;  // 16x16
#pragma unroll
  for (int j = 0; j < 4; ++j) {
    int row = ty + j * 16;
    f32x4 vv = *(const f32x4*)(ip + (size_t)(r0 + row) * NS + c0 + tx * 4);
    u16x4 bb = pkbf4(vv.x, vv.y, vv.z, vv.w);
    t[row][tx * 4 + 0] = bb.x; t[row][tx * 4 + 1] = bb.y;
    t[row][tx * 4 + 2] = bb.z; t[row][tx * 4 + 3] = bb.w;
  }
  __syncthreads();
#pragma unroll
  for (int j = 0; j < 4; ++j) {
    int crow = ty + j * 16;
    u16x4 vv;
    vv.x = t[tx * 4 + 0][crow]; vv.y = t[tx * 4 + 1][crow];
    vv.z = t[tx * 4 + 2][crow]; vv.w = t[tx * 4 + 3][crow];
    *(u16x4*)(op + (size_t)(c0 + crow) * DM + r0 + tx * 4) = vv;
  }
}

// ---------------- fused QKV projection GEMM ----------------
__global__ __launch_bounds__(256) void qkv_k(
    const u16* __restrict__ Xq, const u16* __restrict__ Xk, const u16* __restrict__ Xv,
    const u16* __restrict__ Wq, const u16* __restrict__ Wk, const u16* __restrict__ Wv,
    const float* __restrict__ bq, const float* __restrict__ bk, const float* __restrict__ bv,
    u16* __restrict__ QH, u16* __restrict__ KH, u16* __restrict__ VH) {
  __shared__ __attribute__((aligned(16))) u16 As[128 * 32];
  __shared__ __attribute__((aligned(16))) u16 Bs[128 * 32];
  const int z = blockIdx.z, b = z & 1, which = z >> 1;
  const u16* X = which == 0 ? Xq : which == 1 ? Xk : Xv;
  const u16* W = which == 0 ? Wq : which == 1 ? Wk : Wv;
  const float* bias = which == 0 ? bq : which == 1 ? bk : bv;
  u16* out = which == 0 ? QH : which == 1 ? KH : VH;
  const float sc = which == 0 ? 0.18033688011112042f : 1.0f;  // 0.125*log2e
  const int m0 = blockIdx.x * 128;
  const int c0 = blockIdx.y * 128;
  const u16* Xb = X + (size_t)b * NS * DM;
  const int tid = threadIdx.x;
  const int lane = tid & 63, w = tid >> 6;
  const int wm = w >> 1, wc = w & 1;
  const int qd = lane >> 4, ml = lane & 15;
  const int sml = (ml >> 1) & 3;  // read-side swizzle key

  f32x4 acc[4][4];
#pragma unroll
  for (int i = 0; i < 4; ++i)
#pragma unroll
    for (int j = 0; j < 4; ++j) acc[i][j] = (f32x4){0.f, 0.f, 0.f, 0.f};

  for (int k0 = 0; k0 < DM; k0 += 32) {
    __syncthreads();
#pragma unroll
    for (int it = 0; it < 2; ++it) {
      int ci = it * 256 + tid;
      int row = ci >> 2;
      int jg = (ci & 3) ^ ((ci >> 3) & 3);  // chunk swizzle (row>>1)&3
      gload16(&As[ci * 8], Xb + (size_t)(m0 + row) * DM + k0 + jg * 8);
      gload16(&Bs[ci * 8], W + (size_t)(c0 + row) * DM + k0 + jg * 8);
    }
    __syncthreads();
    short8 af[4], bf[4];
#pragma unroll
    for (int i = 0; i < 4; ++i) {
      af[i] = *(const short8*)&As[(wm * 64 + i * 16 + ml) * 32 + ((qd ^ sml) * 8)];
      bf[i] = *(const short8*)&Bs[(wc * 64 + i * 16 + ml) * 32 + ((qd ^ sml) * 8)];
    }
#pragma unroll
    for (int mi = 0; mi < 4; ++mi)
#pragma unroll
      for (int ci2 = 0; ci2 < 4; ++ci2)
        acc[mi][ci2] = __builtin_amdgcn_mfma_f32_16x16x32_bf16(af[mi], bf[ci2],
                                                               acc[mi][ci2], 0, 0, 0);
  }

  const int cw = c0 + wc * 64;
  const int mw = m0 + wm * 64;
  float bv4[4];
#pragma unroll
  for (int ci2 = 0; ci2 < 4; ++ci2) bv4[ci2] = bias[cw + ci2 * 16 + ml];

  if (which < 2) {
    const int h = ml, d0 = cw >> 4;
    u16* ob = out + ((size_t)(b * NH + h) * NS) * HD;
#pragma unroll
    for (int mi = 0; mi < 4; ++mi) {
#pragma unroll
      for (int r = 0; r < 4; ++r) {
        int n = mw + mi * 16 + qd * 4 + r;
        *(u16x4*)(ob + (size_t)n * HD + d0) =
            pkbf4((acc[mi][0][r] + bv4[0]) * sc, (acc[mi][1][r] + bv4[1]) * sc,
                  (acc[mi][2][r] + bv4[2]) * sc, (acc[mi][3][r] + bv4[3]) * sc);
      }
    }
  } else {
#pragma unroll
    for (int ci2 = 0; ci2 < 4; ++ci2) {
      int c = cw + ci2 * 16 + ml;
      int h = c & 15, d = c >> 4;
#pragma unroll
      for (int mi = 0; mi < 4; ++mi) {
        int nb = mw + mi * 16 + qd * 4;
        *(u16x4*)(out + ((size_t)(b * NH + h) * HD + d) * NS + nb) =
            pkbf4(acc[mi][ci2][0] + bv4[ci2], acc[mi][ci2][1] + bv4[ci2],
                  acc[mi][ci2][2] + bv4[ci2], acc[mi][ci2][3] + bv4[ci2]);
      }
    }
  }
}

// ---------------- output projection, 64x128 tiles (fp32 out) ----------------
// X: [b][n][j] (j = h*64+d, attn output), W: Wm' with permuted columns.
__global__ __launch_bounds__(256) void proj_o(const u16* __restrict__ X,
                                              const u16* __restrict__ W,
                                              const float* __restrict__ bias,
                                              float* __restrict__ out) {
  __shared__ __attribute__((aligned(16))) u16 As[64 * 32];
  __shared__ __attribute__((aligned(16))) u16 Bs[128 * 32];
  const int b = blockIdx.z;
  const int m0 = blockIdx.x * 64;
  const int c0 = blockIdx.y * 128;
  const u16* Xb = X + (size_t)b * NS * DM;
  const int tid = threadIdx.x;
  const int lane = tid & 63, w = tid >> 6;
  const int wm = w >> 1, wc = w & 1;  // wave tile: 32 rows x 64 cols
  const int qd = lane >> 4, ml = lane & 15;
  const int sml = (ml >> 1) & 3;

  f32x4 acc[2][4];
#pragma unroll
  for (int i = 0; i < 2; ++i)
#pragma unroll
    for (int j = 0; j < 4; ++j) acc[i][j] = (f32x4){0.f, 0.f, 0.f, 0.f};

  for (int k0 = 0; k0 < DM; k0 += 32) {
    __syncthreads();
    {  // A: 256 chunks (64 rows x 4), one per thread
      int jg = (tid & 3) ^ ((tid >> 3) & 3);
      int row = tid >> 2;
      gload16(&As[tid * 8], Xb + (size_t)(m0 + row) * DM + k0 + jg * 8);
    }
#pragma unroll
    for (int it = 0; it < 2; ++it) {  // B: 512 chunks (128 rows x 4)
      int ci = it * 256 + tid;
      int row = ci >> 2;
      int jg = (ci & 3) ^ ((ci >> 3) & 3);
      gload16(&Bs[ci * 8], W + (size_t)(c0 + row) * DM + k0 + jg * 8);
    }
    __syncthreads();
    short8 af[2], bf[4];
#pragma unroll
    for (int i = 0; i < 2; ++i)
      af[i] = *(const short8*)&As[(wm * 32 + i * 16 + ml) * 32 + ((qd ^ sml) * 8)];
#pragma unroll
    for (int i = 0; i < 4; ++i)
      bf[i] = *(const short8*)&Bs[(wc * 64 + i * 16 + ml) * 32 + ((qd ^ sml) * 8)];
#pragma unroll
    for (int mi = 0; mi < 2; ++mi)
#pragma unroll
      for (int ci2 = 0; ci2 < 4; ++ci2)
        acc[mi][ci2] = __builtin_amdgcn_mfma_f32_16x16x32_bf16(af[mi], bf[ci2],
                                                               acc[mi][ci2], 0, 0, 0);
  }

  const int cw = c0 + wc * 64;
  const int mw = m0 + wm * 32;
#pragma unroll
  for (int ci2 = 0; ci2 < 4; ++ci2) {
    int c = cw + ci2 * 16 + ml;
    float bv = bias[c];
#pragma unroll
    for (int mi = 0; mi < 2; ++mi) {
      int nb = mw + mi * 16 + qd * 4;
      f32x4 v;
      v.x = acc[mi][ci2][0] + bv; v.y = acc[mi][ci2][1] + bv;
      v.z = acc[mi][ci2][2] + bv; v.w = acc[mi][ci2][3] + bv;
      *(f32x4*)(out + ((size_t)b * DM + c) * NS + nb) = v;
    }
  }
}

// ------- flash attention, 128 q-rows/block, register-P, async dbuf -----------
// Q,K: [bh][n][d] (Q pre-scaled), V: [bh][d][n]. grid (NS/128, 32).
// Wave w: q-rows w*32..w*32+31 as two 16-row fragment sets. Each staged K/V
// tile + each bk/vb ds_read feeds BOTH sets (2x arithmetic intensity vs R12).
// S^T = mfma(K,Q); PV = mfma(V,P) -> O^T; epilogue writes [b][n][h*64+d].
__global__ __launch_bounds__(256) void attn_k(const u16* __restrict__ Q,
                                              const u16* __restrict__ K,
                                              const u16* __restrict__ V,
                                              u16* __restrict__ XO) {
  __shared__ __attribute__((aligned(16))) u16 Ks[2 * 2 * 2048];  // [buf][slab][64][32]
  __shared__ __attribute__((aligned(16))) u16 Vs[2 * 2 * 2048];  // [buf][slab][64 d][32]
  const int bh = blockIdx.y, b = bh >> 4, h = bh & 15;
  const int n0 = blockIdx.x * 128;
  const u16* Qb = Q + (size_t)bh * NS * HD;
  const u16* Kb = K + (size_t)bh * NS * HD;
  const u16* Vb = V + (size_t)bh * HD * NS;
  const int tid = threadIdx.x, lane = tid & 63, w = tid >> 6;
  const int qd = lane >> 4, ml = lane & 15;
  const int sml = (ml >> 1) & 3;

  // Q fragments, two 16-row sets, straight from global
  short8 aq[2][2];
#pragma unroll
  for (int s = 0; s < 2; ++s) {
    const u16* qr = Qb + (size_t)(n0 + w * 32 + s * 16 + ml) * HD + qd * 8;
    aq[s][0] = *(const short8*)qr;
    aq[s][1] = *(const short8*)(qr + 32);
  }

  const int srow = tid >> 2;                       // staging row (key or d)
  const int jg = (tid & 3) ^ ((tid >> 3) & 3);     // swizzled 16B chunk

  // prologue: tile 0 -> buf 0
#pragma unroll
  for (int s = 0; s < 2; ++s) {
    gload16(&Ks[s * 2048 + tid * 8], Kb + (size_t)srow * HD + s * 32 + jg * 8);
    gload16(&Vs[s * 2048 + tid * 8], Vb + (size_t)srow * NS + s * 32 + jg * 8);
  }
  __syncthreads();

  f32x4 O[2][4];
#pragma unroll
  for (int s = 0; s < 2; ++s)
#pragma unroll
    for (int i = 0; i < 4; ++i) O[s][i] = (f32x4){0.f, 0.f, 0.f, 0.f};
  f32x4 ls0 = (f32x4){0.f, 0.f, 0.f, 0.f};
  f32x4 ls1 = (f32x4){0.f, 0.f, 0.f, 0.f};

  for (int kb = 0; kb < NS / 64; ++kb) {
    const int cur = kb & 1, nxt = cur ^ 1;
    if (kb < NS / 64 - 1) {  // prefetch tile kb+1 into the other buffer
#pragma unroll
      for (int s = 0; s < 2; ++s) {
        gload16(&Ks[(nxt * 2 + s) * 2048 + tid * 8],
                Kb + (size_t)((kb + 1) * 64 + srow) * HD + s * 32 + jg * 8);
        gload16(&Vs[(nxt * 2 + s) * 2048 + tid * 8],
                Vb + (size_t)srow * NS + (kb + 1) * 64 + s * 32 + jg * 8);
      }
    }

    // S^T = K Q^T for both q-sets; each bk read feeds 2 MFMAs
    const u16* kbase = &Ks[cur * 2 * 2048];
    s16x4 pf[2][4];
#pragma unroll
    for (int f = 0; f < 4; ++f) {
      f32x4 S0 = (f32x4){0.f, 0.f, 0.f, 0.f};
      f32x4 S1 = (f32x4){0.f, 0.f, 0.f, 0.f};
#pragma unroll
      for (int ks = 0; ks < 2; ++ks) {
        short8 bk = *(const short8*)&kbase[ks * 2048 + (f * 16 + ml) * 32 +
                                           ((qd ^ sml) * 8)];
        S0 = __builtin_amdgcn_mfma_f32_16x16x32_bf16(bk, aq[0][ks], S0, 0, 0, 0);
        S1 = __builtin_amdgcn_mfma_f32_16x16x32_bf16(bk, aq[1][ks], S1, 0, 0, 0);
      }
      f32x4 p;
      p.x = __builtin_amdgcn_exp2f(S0[0]); p.y = __builtin_amdgcn_exp2f(S0[1]);
      p.z = __builtin_amdgcn_exp2f(S0[2]); p.w = __builtin_amdgcn_exp2f(S0[3]);
      ls0 += p;
      pf[0][f] = pkbf4s(p.x, p.y, p.z, p.w);
      p.x = __builtin_amdgcn_exp2f(S1[0]); p.y = __builtin_amdgcn_exp2f(S1[1]);
      p.z = __builtin_amdgcn_exp2f(S1[2]); p.w = __builtin_amdgcn_exp2f(S1[3]);
      ls1 += p;
      pf[1][f] = pkbf4s(p.x, p.y, p.z, p.w);
    }

    // O^T += V P for both q-sets; each vb read feeds 2 MFMAs
    const u16* vbase = &Vs[cur * 2 * 2048];
#pragma unroll
    for (int t = 0; t < 4; ++t) {
      const int vs = t >> 1;
      const int voff = ((((t & 1) * 2 + (qd >> 1)) ^ sml) * 8) + (qd & 1) * 4;
#pragma unroll
      for (int df = 0; df < 4; ++df) {
        s16x4 vb = *(const s16x4*)&vbase[vs * 2048 + (df * 16 + ml) * 32 + voff];
        O[0][df] = MFMA_PV(vb, pf[0][t], O[0][df]);
        O[1][df] = MFMA_PV(vb, pf[1][t], O[1][df]);
      }
    }
    __syncthreads();  // readers of cur done + prefetch into nxt drained
  }

  // epilogue per q-set: reduce l over quads, normalize, coalesced store
#pragma unroll
  for (int s = 0; s < 2; ++s) {
    f32x4 l4 = s == 0 ? ls0 : ls1;
    float lsum = (l4.x + l4.y) + (l4.z + l4.w);
    lsum += __shfl_xor(lsum, 16);
    lsum += __shfl_xor(lsum, 32);
    const float linv = 1.f / lsum;  // qrow = ml
    u16* xb = XO + ((size_t)(b * NS) + n0 + w * 32 + s * 16 + ml) * DM + h * 64;
#pragma unroll
    for (int df = 0; df < 4; ++df) {
      *(u16x4*)(xb + df * 16 + qd * 4) =
          pkbf4(O[s][df][0] * linv, O[s][df][1] * linv,
                O[s][df][2] * linv, O[s][df][3] * linv);
    }
  }
}

extern "C" void kernel_launch(void* const* d_in, const int* in_sizes, int n_in,
                              void* d_out, int out_size, void* d_ws, size_t ws_size,
                              hipStream_t stream) {
  const float* query = (const float*)d_in[0];
  const float* key = (const float*)d_in[1];
  const float* value = (const float*)d_in[2];
  const float* Wq = (const float*)d_in[3]; const float* bq = (const float*)d_in[4];
  const float* Wk = (const float*)d_in[5]; const float* bk = (const float*)d_in[6];
  const float* Wv = (const float*)d_in[7]; const float* bv = (const float*)d_in[8];
  const float* Wm = (const float*)d_in[9]; const float* bm = (const float*)d_in[10];

  u16* ws = (u16*)d_ws;
  const size_t TS = (size_t)2 * NS * DM;   // 4,194,304 u16 elems
  const size_t WSZ = (size_t)DM * DM;
  u16* XTq = ws;
  u16* XTk = ws + TS;
  u16* XTv = ws + 2 * TS;
  u16* QH = ws + 3 * TS;
  u16* KH = ws + 4 * TS;
  u16* VH = ws + 5 * TS;
  u16* Wqb = ws + 6 * TS;
  u16* Wkb = Wqb + WSZ;
  u16* Wvb = Wkb + WSZ;
  u16* Wmb = Wvb + WSZ;  // Wm with permuted columns (j = h*64+d)
  u16* XO = XTq;         // attn out [b][n][h*64+d]; XTq dead after qkv_k

  cvtw_k<<<dim3(WSZ / 1024, 4), 256, 0, stream>>>(Wq, Wk, Wv, Wm, Wqb, Wkb, Wvb, Wmb);

  dim3 tb(16, 16);
  trf3_k<<<dim3(NS / 64, DM / 64, 6), tb, 0, stream>>>(query, key, value, XTq, XTk, XTv);

  qkv_k<<<dim3(NS / 128, DM / 128, 6), 256, 0, stream>>>(
      XTq, XTk, XTv, Wqb, Wkb, Wvb, bq, bk, bv, QH, KH, VH);

  attn_k<<<dim3(NS / 128, 32), 256, 0, stream>>>(QH, KH, VH, XO);

  proj_o<<<dim3(NS / 64, DM / 128, 2), 256, 0, stream>>>(XO, Wmb, bm, (float*)d_out);
}